// Round 2
// baseline (3747.110 us; speedup 1.0000x reference)
//
#include <hip/hip_runtime.h>
#include <hip/hip_bf16.h>

#define B_  4
#define L_  1024
#define DM  1024
#define DI  2048
#define NS  16
#define RK  64
#define MT  (B_ * L_)   // 4096 tokens

typedef unsigned short u16;

__device__ __forceinline__ float bf2f(u16 u) {
  union { unsigned int i; float f; } c; c.i = ((unsigned int)u) << 16; return c.f;
}
__device__ __forceinline__ u16 f2bf(float f) {
  union { float f; unsigned int i; } c; c.f = f;
  unsigned int x = c.i;
  unsigned int r = (x + 0x7fffu + ((x >> 16) & 1u)) >> 16;  // RNE
  return (u16)r;
}

// ---------------------------------------------------------------------------
// dtype detect: Alog[0]=log(1)=0.  fp32 -> first u32 == 0x00000000.
// bf16 -> first u32 == (bf16(log2)<<16)|0 = 0x3F310000 != 0.
// flag: 1 = inputs are bf16, 0 = inputs are fp32.
// ---------------------------------------------------------------------------
__global__ void detect_k(const unsigned int* __restrict__ alog, int* __restrict__ flag) {
  *flag = (alog[0] != 0u) ? 1 : 0;
}

// Convert any input tensor to a bf16 workspace copy (pass-through if already bf16).
__global__ __launch_bounds__(256)
void cvt_k(const void* __restrict__ src, u16* __restrict__ dst, int n,
           const int* __restrict__ flag) {
  int i = blockIdx.x * 256 + threadIdx.x;
  if (i >= n) return;
  if (*flag) dst[i] = ((const u16*)src)[i];
  else       dst[i] = f2bf(((const float*)src)[i]);
}

// Final store: write d_out in the detected dtype.
__global__ __launch_bounds__(256)
void store_out_k(const u16* __restrict__ src, void* __restrict__ dst,
                 const int* __restrict__ flag) {
  int i = blockIdx.x * 256 + threadIdx.x;   // < MT*DM
  if (*flag) ((u16*)dst)[i] = src[i];
  else       ((float*)dst)[i] = bf2f(src[i]);
}

// ---------------------------------------------------------------------------
// Generic bf16 GEMM: C[M,N] = act(A[M,K] @ W[K,N] + bias)
// 64x64 block tile, BK=16, 256 threads, 4x4 register tile, fp32 accumulate.
// ACT: 0 = none, 1 = softplus, 2 = sigmoid
// ---------------------------------------------------------------------------
#define BM 64
#define BN 64
#define BK 16

template<int ACT>
__global__ __launch_bounds__(256)
void gemm_k(const u16* __restrict__ A, int lda,
            const u16* __restrict__ W, int ldw,
            const u16* __restrict__ bias,
            u16* __restrict__ C, int ldc,
            int M, int N, int K)
{
  __shared__ __align__(16) float As[BK][BM + 4];
  __shared__ __align__(16) float Bs[BK][BN];

  const int tid = threadIdx.x;
  const int bm0 = blockIdx.y * BM;
  const int bn0 = blockIdx.x * BN;
  const int tmg = tid >> 4;          // 0..15 -> output rows tmg*4..+3
  const int tng = tid & 15;          // 0..15 -> output cols tng*4..+3
  const int ar  = tid >> 2;          // 0..63  A-tile row
  const int ak  = (tid & 3) << 2;    // 0,4,8,12
  const int br  = tid >> 4;          // 0..15  B-tile k-row
  const int bc  = (tid & 15) << 2;   // 0..60

  float acc[4][4] = {};

  for (int k0 = 0; k0 < K; k0 += BK) {
    {   // stage A tile (M, K multiples of tile for our shapes)
      const u16* ap = A + (size_t)(bm0 + ar) * lda + (k0 + ak);
      ushort4 av = *reinterpret_cast<const ushort4*>(ap);
      As[ak + 0][ar] = bf2f(av.x);
      As[ak + 1][ar] = bf2f(av.y);
      As[ak + 2][ar] = bf2f(av.z);
      As[ak + 3][ar] = bf2f(av.w);
    }
    {   // stage B tile (guard N: xproj has N=96)
      int gn = bn0 + bc;
      const u16* bp = W + (size_t)(k0 + br) * ldw + gn;
      float4 bv;
      if (gn + 3 < N) {
        ushort4 wv = *reinterpret_cast<const ushort4*>(bp);
        bv.x = bf2f(wv.x); bv.y = bf2f(wv.y); bv.z = bf2f(wv.z); bv.w = bf2f(wv.w);
      } else {
        bv.x = (gn + 0 < N) ? bf2f(bp[0]) : 0.f;
        bv.y = (gn + 1 < N) ? bf2f(bp[1]) : 0.f;
        bv.z = (gn + 2 < N) ? bf2f(bp[2]) : 0.f;
        bv.w = (gn + 3 < N) ? bf2f(bp[3]) : 0.f;
      }
      *reinterpret_cast<float4*>(&Bs[br][bc]) = bv;
    }
    __syncthreads();
    #pragma unroll
    for (int kk = 0; kk < BK; ++kk) {
      float4 a = *reinterpret_cast<const float4*>(&As[kk][tmg << 2]);
      float4 b = *reinterpret_cast<const float4*>(&Bs[kk][tng << 2]);
      float av4[4] = {a.x, a.y, a.z, a.w};
      float bv4[4] = {b.x, b.y, b.z, b.w};
      #pragma unroll
      for (int i = 0; i < 4; ++i)
        #pragma unroll
        for (int j = 0; j < 4; ++j)
          acc[i][j] += av4[i] * bv4[j];
    }
    __syncthreads();
  }

  #pragma unroll
  for (int i = 0; i < 4; ++i) {
    int row = bm0 + (tmg << 2) + i;
    #pragma unroll
    for (int j = 0; j < 4; ++j) {
      int col = bn0 + (tng << 2) + j;
      if (col < N) {
        float v = acc[i][j];
        if (bias) v += bf2f(bias[col]);
        if (ACT == 1) v = (v > 20.f) ? v : log1pf(__expf(v));          // softplus
        if (ACT == 2) v = 1.f / (1.f + __expf(-v));                    // sigmoid
        C[(size_t)row * ldc + col] = f2bf(v);
      }
    }
  }
}

// ---------------------------------------------------------------------------
// Depthwise causal conv1d (width 4) + SiLU.  u lives in xz cols [0, DI).
// ---------------------------------------------------------------------------
__global__ __launch_bounds__(256)
void conv_silu_k(const u16* __restrict__ xz,   // [MT, 2*DI]
                 const u16* __restrict__ cw,   // [DI, 4]
                 const u16* __restrict__ cb,   // [DI]
                 u16* __restrict__ uc)         // [MT, DI]
{
  int e = blockIdx.x * 256 + threadIdx.x;      // < MT*DI = 2^23
  int d = e & (DI - 1);
  int t = (e >> 11) & (L_ - 1);
  int b = e >> 21;
  float acc = bf2f(cb[d]);
  #pragma unroll
  for (int k = 0; k < 4; ++k) {
    int ts = t + k - 3;                         // w[:,3] hits current token
    if (ts >= 0)
      acc += bf2f(xz[((size_t)(b * L_ + ts) << 12) + d]) * bf2f(cw[(d << 2) + k]);
  }
  float s = acc / (1.f + __expf(-acc));         // silu
  uc[(size_t)e] = f2bf(s);
}

// ---------------------------------------------------------------------------
// Selective scan. One thread per (b, d, n); 16-lane shuffle reduce over n.
// Fuses the +uc*Dp skip and the silu(z) output gate.
// NOTE: ys may alias delta (same-thread, same-iteration data dep only),
// so no __restrict__ on those two.
// ---------------------------------------------------------------------------
__global__ __launch_bounds__(256)
void scan_k(const u16* __restrict__ uc,     // [MT, DI]
            const u16* delta,               // [MT, DI]
            const u16* __restrict__ dbl,    // [MT, 96]  (dt | B | C)
            const u16* __restrict__ xz,     // [MT, 4096], z at col 2048+d
            const u16* __restrict__ Alog,   // [DI, NS]
            const u16* __restrict__ Dp,     // [DI]
            u16* ys)                        // [MT, DI]  (may alias delta)
{
  int g = blockIdx.x * 256 + threadIdx.x;   // < B_*DI*NS = 2^17
  int n = g & 15;
  int d = (g >> 4) & (DI - 1);
  int b = g >> 15;
  float Adn = -__expf(bf2f(Alog[(d << 4) + n]));
  float Dv  = bf2f(Dp[d]);
  float h = 0.f;
  size_t rowbase = (size_t)b * L_;
  for (int t = 0; t < L_; ++t) {
    size_t row = rowbase + t;
    float dv = bf2f(delta[row * DI + d]);
    float uv = bf2f(uc[row * DI + d]);
    float Bv = bf2f(dbl[row * 96 + 64 + n]);
    float Cv = bf2f(dbl[row * 96 + 80 + n]);
    float dA = __expf(dv * Adn);
    h = dA * h + (dv * uv) * Bv;
    float c = h * Cv;
    c += __shfl_xor(c, 1);
    c += __shfl_xor(c, 2);
    c += __shfl_xor(c, 4);
    c += __shfl_xor(c, 8);
    if (n == 0) {
      float z = bf2f(xz[(row << 12) + DI + d]);
      float y = c + uv * Dv;
      y *= z / (1.f + __expf(-z));            // * silu(z)
      ys[row * DI + d] = f2bf(y);
    }
  }
}

// ---------------------------------------------------------------------------
// Small elementwise kernels
// ---------------------------------------------------------------------------
__global__ __launch_bounds__(256)
void flip_k(const u16* __restrict__ x, u16* __restrict__ xb)
{
  int e = blockIdx.x * 256 + threadIdx.x;    // < MT*DM = 2^22
  int c = e & (DM - 1);
  int t = (e >> 10) & (L_ - 1);
  int b = e >> 20;
  xb[e] = x[((size_t)(b * L_ + (L_ - 1 - t)) << 10) + c];
}

__global__ __launch_bounds__(256)
void concat_k(const u16* __restrict__ yf, const u16* __restrict__ yb,
              u16* __restrict__ cat)
{
  int e = blockIdx.x * 256 + threadIdx.x;    // < MT*2*DM = 2^23
  int c = e & (2 * DM - 1);
  int row = e >> 11;
  int b = row >> 10, t = row & (L_ - 1);
  u16 v;
  if (c < DM) v = yf[((size_t)row << 10) + c];
  else        v = yb[((size_t)(b * L_ + (L_ - 1 - t)) << 10) + (c - DM)];
  cat[e] = v;
}

__global__ __launch_bounds__(256)
void combine_k(const u16* __restrict__ g, const u16* __restrict__ yf,
               const u16* __restrict__ yb, u16* __restrict__ yc)
{
  int e = blockIdx.x * 256 + threadIdx.x;    // < MT*DM
  int c = e & (DM - 1);
  int row = e >> 10;
  int b = row >> 10, t = row & (L_ - 1);
  float gv = bf2f(g[e]);
  float fv = bf2f(yf[e]);
  float bv = bf2f(yb[((size_t)(b * L_ + (L_ - 1 - t)) << 10) + c]);
  yc[e] = f2bf(gv * fv + (1.f - gv) * bv);
}

// ---------------------------------------------------------------------------
// Launch
// ---------------------------------------------------------------------------
extern "C" void kernel_launch(void* const* d_in, const int* in_sizes, int n_in,
                              void* d_out, int out_size, void* d_ws, size_t ws_size,
                              hipStream_t stream)
{
  char* ws = (char*)d_ws;
  const size_t MB = 1ull << 20;

  // --- pipeline buffers (bf16) ---
  u16* xz    = (u16*)(ws + 0);         // 32 MB [MT, 4096]   (u | z)
  u16* uc    = (u16*)(ws + 32 * MB);   // 16 MB [MT, DI]
  u16* dbl   = (u16*)(ws + 48 * MB);   //  1 MB [MT, 96]
  u16* delta = (u16*)(ws + 49 * MB);   // 16 MB [MT, DI]; ys aliases this
  u16* yf    = (u16*)(ws + 65 * MB);   //  8 MB [MT, DM]
  u16* yb    = (u16*)(ws + 73 * MB);   //  8 MB [MT, DM]  (flipped time order)
  u16* xb    = (u16*)(ws + 81 * MB);   //  8 MB [MT, DM]
  u16* xc    = (u16*)(ws + 89 * MB);   //  8 MB bf16 copy of x
  // tail overlays (xz region dead by then):
  u16* cat   = xz;                     // 16 MB [MT, 2*DM]
  u16* gbuf  = (u16*)(ws + 16 * MB);   //  8 MB [MT, DM]
  u16* yc    = (u16*)(ws + 24 * MB);   //  8 MB [MT, DM]
  u16* outb  = (u16*)(ws + 0);         //  8 MB final bf16 (cat dead after gate)

  // --- bf16 weight copies ---
  u16* w_inproj[2], *w_convw[2], *w_convb[2], *w_xproj[2], *w_dtw[2];
  u16* w_dtb[2], *w_alog[2], *w_dp[2], *w_outp[2];
  for (int s = 0; s < 2; ++s) {
    char* base = ws + (97 + 14 * s) * MB;
    w_inproj[s] = (u16*)(base);                         // 8 MB
    w_outp[s]   = (u16*)(base + 8 * MB);                // 4 MB
    w_xproj[s]  = (u16*)(base + 12 * MB);               // 384 KB
    w_dtw[s]    = (u16*)(base + 12 * MB + 393216);      // 256 KB
    w_alog[s]   = (u16*)(base + 12 * MB + 655360);      // 64 KB
    w_convw[s]  = (u16*)(base + 12 * MB + 720896);      // 16 KB
    w_convb[s]  = (u16*)(base + 12 * MB + 737280);      // 4 KB
    w_dtb[s]    = (u16*)(base + 12 * MB + 741376);      // 4 KB
    w_dp[s]     = (u16*)(base + 12 * MB + 745472);      // 4 KB
  }
  u16* w_gw = (u16*)(ws + 125 * MB);   // 4 MB
  u16* w_pw = (u16*)(ws + 129 * MB);   // 2 MB
  u16* w_gb = (u16*)(ws + 131 * MB);
  u16* w_pb = (u16*)(ws + 131 * MB + 4096);
  int* flag = (int*)(ws + 131 * MB + 8192);

  dim3 blk(256);

  // 1) dtype detect off Alog_f (d_in[7]): log(1)=0 leading word iff fp32
  detect_k<<<1, 1, 0, stream>>>((const unsigned int*)d_in[7], flag);

  // 2) convert all inputs to bf16 ws copies
  auto cvt = [&](const void* src, u16* dst, int n) {
    cvt_k<<<(n + 255) / 256, blk, 0, stream>>>(src, dst, n, flag);
  };
  cvt(d_in[0], xc, MT * DM);
  for (int s = 0; s < 2; ++s) {
    int o = 9 * s;   // forward block at 1..9, backward at 10..18
    cvt(d_in[1 + o], w_inproj[s], DM * 2 * DI);
    cvt(d_in[2 + o], w_convw[s], DI * 4);
    cvt(d_in[3 + o], w_convb[s], DI);
    cvt(d_in[4 + o], w_xproj[s], DI * 96);
    cvt(d_in[5 + o], w_dtw[s], RK * DI);
    cvt(d_in[6 + o], w_dtb[s], DI);
    cvt(d_in[7 + o], w_alog[s], DI * NS);
    cvt(d_in[8 + o], w_dp[s], DI);
    cvt(d_in[9 + o], w_outp[s], DI * DM);
  }
  cvt(d_in[19], w_gw, 2 * DM * DM);
  cvt(d_in[20], w_gb, DM);
  cvt(d_in[21], w_pw, DM * DM);
  cvt(d_in[22], w_pb, DM);

  // 3) time-flip of x for the backward direction
  flip_k<<<MT * DM / 256, blk, 0, stream>>>(xc, xb);

  for (int s = 0; s < 2; ++s) {
    const u16* xin = (s == 0) ? xc : xb;
    u16* ydir = (s == 0) ? yf : yb;
    // xz = xin @ inproj          [4096 x 4096 x 1024]
    gemm_k<0><<<dim3(2 * DI / BN, MT / BM), blk, 0, stream>>>(
        xin, DM, w_inproj[s], 2 * DI, nullptr, xz, 2 * DI, MT, 2 * DI, DM);
    // uc = silu(causal_conv(u))
    conv_silu_k<<<MT * DI / 256, blk, 0, stream>>>(xz, w_convw[s], w_convb[s], uc);
    // dbl = uc @ xproj           [4096 x 96 x 2048]
    gemm_k<0><<<dim3((96 + BN - 1) / BN, MT / BM), blk, 0, stream>>>(
        uc, DI, w_xproj[s], 96, nullptr, dbl, 96, MT, 96, DI);
    // delta = softplus(dbl[:, :64] @ dt_w + dt_b)   [4096 x 2048 x 64]
    gemm_k<1><<<dim3(DI / BN, MT / BM), blk, 0, stream>>>(
        dbl, 96, w_dtw[s], DI, w_dtb[s], delta, DI, MT, DI, RK);
    // selective scan (+ skip + z-gate); ys aliases delta
    scan_k<<<B_ * DI * NS / 256, blk, 0, stream>>>(
        uc, delta, dbl, xz, w_alog[s], w_dp[s], delta);
    // ydir = ys @ outproj        [4096 x 1024 x 2048]
    gemm_k<0><<<dim3(DM / BN, MT / BM), blk, 0, stream>>>(
        delta, DI, w_outp[s], DM, nullptr, ydir, DM, MT, DM, DI);
  }

  concat_k<<<MT * 2 * DM / 256, blk, 0, stream>>>(yf, yb, cat);
  // g = sigmoid(cat @ gate_w + gate_b)   [4096 x 1024 x 2048]
  gemm_k<2><<<dim3(DM / BN, MT / BM), blk, 0, stream>>>(
      cat, 2 * DM, w_gw, DM, w_gb, gbuf, DM, MT, DM, 2 * DM);
  combine_k<<<MT * DM / 256, blk, 0, stream>>>(gbuf, yf, yb, yc);
  // out = yc @ proj_w + proj_b           [4096 x 1024 x 1024]
  gemm_k<0><<<dim3(DM / BN, MT / BM), blk, 0, stream>>>(
      yc, DM, w_pw, DM, w_pb, outb, DM, MT, DM, DM);
  // 4) store in detected dtype
  store_out_k<<<MT * DM / 256, blk, 0, stream>>>(outb, d_out, flag);
}

// Round 3
// 1161.395 us; speedup vs baseline: 3.2264x; 3.2264x over previous
//
#include <hip/hip_runtime.h>
#include <hip/hip_bf16.h>

#define B_  4
#define L_  1024
#define DM  1024
#define DI  2048
#define NS  16
#define RK  64
#define MT  (B_ * L_)   // 4096 tokens
#define NC  16          // scan chunks
#define CH  (L_ / NC)   // 64 steps per chunk

typedef unsigned short u16;
typedef __attribute__((ext_vector_type(8))) short  bh8;   // 8 bf16 (4 VGPRs)
typedef __attribute__((ext_vector_type(8))) unsigned short us8;
typedef __attribute__((ext_vector_type(4))) float  f4;

__device__ __forceinline__ float bf2f(u16 u) {
  union { unsigned int i; float f; } c; c.i = ((unsigned int)u) << 16; return c.f;
}
__device__ __forceinline__ u16 f2bf(float f) {
  union { float f; unsigned int i; } c; c.f = f;
  unsigned int x = c.i;
  unsigned int r = (x + 0x7fffu + ((x >> 16) & 1u)) >> 16;  // RNE
  return (u16)r;
}

// ---------------------------------------------------------------------------
// dtype detect: Alog[0]=log(1)=0.  fp32 -> first u32 == 0.  bf16 -> 0x3F310000.
// flag: 1 = bf16 inputs, 0 = fp32 inputs.
// ---------------------------------------------------------------------------
__global__ void detect_k(const unsigned int* __restrict__ alog, int* __restrict__ flag) {
  *flag = (alog[0] != 0u) ? 1 : 0;
}

__global__ __launch_bounds__(256)
void cvt_k(const void* __restrict__ src, u16* __restrict__ dst, int n,
           const int* __restrict__ flag) {
  int i = blockIdx.x * 256 + threadIdx.x;
  if (i >= n) return;
  if (*flag) dst[i] = ((const u16*)src)[i];
  else       dst[i] = f2bf(((const float*)src)[i]);
}

__global__ __launch_bounds__(256)
void store_out_k(const u16* __restrict__ src, void* __restrict__ dst,
                 const int* __restrict__ flag) {
  int i = blockIdx.x * 256 + threadIdx.x;   // < MT*DM
  if (*flag) ((u16*)dst)[i] = src[i];
  else       ((float*)dst)[i] = bf2f(src[i]);
}

// ---------------------------------------------------------------------------
// Tiled transpose with dtype convert: src[R][C] (flag dtype) -> dst[C][R] bf16.
// ---------------------------------------------------------------------------
__global__ __launch_bounds__(256)
void tpose_k(const void* __restrict__ src, u16* __restrict__ dst,
             int R, int C, const int* __restrict__ flag) {
  __shared__ u16 tile[32][33];
  int c0 = blockIdx.x * 32, r0 = blockIdx.y * 32;
  int tx = threadIdx.x & 31, ty = threadIdx.x >> 5;   // ty 0..7
  int isbf = *flag;
  #pragma unroll
  for (int i = 0; i < 4; ++i) {
    int r = r0 + ty + i * 8, c = c0 + tx;
    u16 v = 0;
    if (r < R && c < C)
      v = isbf ? ((const u16*)src)[(size_t)r * C + c]
               : f2bf(((const float*)src)[(size_t)r * C + c]);
    tile[ty + i * 8][tx] = v;
  }
  __syncthreads();
  #pragma unroll
  for (int i = 0; i < 4; ++i) {
    int c = c0 + ty + i * 8, r = r0 + tx;   // dst row = src col
    if (c < C && r < R)
      dst[(size_t)c * R + r] = tile[tx][ty + i * 8];
  }
}

// ---------------------------------------------------------------------------
// MFMA GEMM: C[M,N] = act(A[M,K] @ W[K,N] + bias), W given pre-transposed as
// Wt[N][K].  128x128 tile, BK=32, 256 thr = 4 waves (2x2 of 64x64), 4x4
// mfma_f32_16x16x32_bf16 per wave per K-step.  fp32 accum.
// A-frag: A[m=lane&15][k=quad*8+j]; B-frag: B[k=quad*8+j][n=lane&15];
// C/D: col=lane&15, row=quad*4+reg  (learn_hip m89/m91 verified).
// FLIP: read A rows time-reversed (row ^ 1023) for the backward direction.
// ACT: 0 none, 1 softplus, 2 sigmoid.
// ---------------------------------------------------------------------------
template<int ACT, int FLIP>
__global__ __launch_bounds__(256, 2)
void gemm_mfma(const u16* __restrict__ A, int lda,
               const u16* __restrict__ Wt,
               const u16* __restrict__ bias,
               u16* __restrict__ C, int ldc,
               int M, int N, int K)
{
  __shared__ __align__(16) u16 As[128][40];   // +8 pad: 80B rows, 16B aligned
  __shared__ __align__(16) u16 Bs[128][40];

  const int tid  = threadIdx.x;
  const int lane = tid & 63;
  const int w    = tid >> 6;
  const int wm   = (w >> 1) * 64, wn = (w & 1) * 64;
  const int bm0  = blockIdx.y * 128, bn0 = blockIdx.x * 128;
  const int l15  = lane & 15, quad = lane >> 4;
  const int ar   = tid >> 2;            // 0..63
  const int ak   = (tid & 3) * 8;       // 0,8,16,24

  f4 acc[4][4] = {};

  for (int k0 = 0; k0 < K; k0 += 32) {
    #pragma unroll
    for (int h = 0; h < 2; ++h) {
      int m = bm0 + ar + h * 64;
      int msrc = FLIP ? (m ^ (L_ - 1)) : m;
      bh8 av = *(const bh8*)(A + (size_t)msrc * lda + k0 + ak);
      *(bh8*)&As[ar + h * 64][ak] = av;
      int n = bn0 + ar + h * 64;
      bh8 bv = {0, 0, 0, 0, 0, 0, 0, 0};
      if (n < N) bv = *(const bh8*)(Wt + (size_t)n * K + k0 + ak);
      *(bh8*)&Bs[ar + h * 64][ak] = bv;
    }
    __syncthreads();
    bh8 af[4], bf[4];
    #pragma unroll
    for (int i = 0; i < 4; ++i) {
      af[i] = *(const bh8*)&As[wm + i * 16 + l15][quad * 8];
      bf[i] = *(const bh8*)&Bs[wn + i * 16 + l15][quad * 8];
    }
    #pragma unroll
    for (int i = 0; i < 4; ++i)
      #pragma unroll
      for (int j = 0; j < 4; ++j)
        acc[i][j] = __builtin_amdgcn_mfma_f32_16x16x32_bf16(af[i], bf[j], acc[i][j], 0, 0, 0);
    __syncthreads();
  }

  #pragma unroll
  for (int j = 0; j < 4; ++j) {
    int col = bn0 + wn + j * 16 + l15;
    if (col >= N) continue;
    float bv = bias ? bf2f(bias[col]) : 0.f;
    #pragma unroll
    for (int i = 0; i < 4; ++i) {
      #pragma unroll
      for (int r = 0; r < 4; ++r) {
        int row = bm0 + wm + i * 16 + quad * 4 + r;
        float v = acc[i][j][r] + bv;
        if (ACT == 1) v = (v > 20.f) ? v : log1pf(__expf(v));
        if (ACT == 2) v = 1.f / (1.f + __expf(-v));
        C[(size_t)row * ldc + col] = f2bf(v);
      }
    }
  }
}

// ---------------------------------------------------------------------------
// Depthwise causal conv1d (width 4) + SiLU.  u lives in xz cols [0, DI).
// ---------------------------------------------------------------------------
__global__ __launch_bounds__(256)
void conv_silu_k(const u16* __restrict__ xz,   // [MT, 2*DI]
                 const u16* __restrict__ cw,   // [DI, 4]
                 const u16* __restrict__ cb,   // [DI]
                 u16* __restrict__ uc)         // [MT, DI]
{
  int e = blockIdx.x * 256 + threadIdx.x;      // < MT*DI
  int d = e & (DI - 1);
  int t = (e >> 11) & (L_ - 1);
  int b = e >> 21;
  float acc = bf2f(cb[d]);
  #pragma unroll
  for (int k = 0; k < 4; ++k) {
    int ts = t + k - 3;                         // w[:,3] hits current token
    if (ts >= 0)
      acc += bf2f(xz[((size_t)(b * L_ + ts) << 12) + d]) * bf2f(cw[(d << 2) + k]);
  }
  uc[(size_t)e] = f2bf(acc / (1.f + __expf(-acc)));
}

// ---------------------------------------------------------------------------
// Chunked selective scan (3 passes). Thread = (b, d, chunk), h[16] in regs.
// h_t = exp(delta_t*A) * h_{t-1} + (delta_t*u_t)*B_t ;  y_t = <h_t, C_t>.
// Pass A: per-chunk affine map  h_end = P*h0 + S.
// Pass B: compose maps across chunks -> h_start per chunk.
// Pass C: re-run chunk from h_start, emit y (+ skip + silu(z) gate).
// P,S,hstart layout: [b][c][n][d] fp32 (coalesced over d-lanes).
// ---------------------------------------------------------------------------
__global__ __launch_bounds__(256)
void scanA_k(const u16* __restrict__ delta, const u16* __restrict__ uc,
             const u16* __restrict__ dbl, const u16* __restrict__ Alog,
             float* __restrict__ P, float* __restrict__ S)
{
  int g = blockIdx.x * 256 + threadIdx.x;   // < B_*NC*DI = 131072
  int d = g & (DI - 1);
  int c = (g >> 11) & (NC - 1);
  int b = g >> 15;
  us8 al0 = *(const us8*)&Alog[d * NS];
  us8 al1 = *(const us8*)&Alog[d * NS + 8];
  float A2[NS], Pv[NS], Sv[NS];
  #pragma unroll
  for (int n = 0; n < 8; ++n) { A2[n] = -__expf(bf2f(al0[n])); A2[n + 8] = -__expf(bf2f(al1[n])); }
  #pragma unroll
  for (int n = 0; n < NS; ++n) { Pv[n] = 1.f; Sv[n] = 0.f; }
  int t0 = c * CH;
  for (int t = t0; t < t0 + CH; ++t) {
    size_t row = (size_t)b * L_ + t;
    float dv = bf2f(delta[row * DI + d]);
    float uv = bf2f(uc[row * DI + d]);
    float du = dv * uv;
    us8 b0 = *(const us8*)&dbl[row * 96 + 64];
    us8 b1 = *(const us8*)&dbl[row * 96 + 72];
    #pragma unroll
    for (int n = 0; n < NS; ++n) {
      float Bv = (n < 8) ? bf2f(b0[n & 7]) : bf2f(b1[n & 7]);
      float dA = __expf(dv * A2[n]);
      Sv[n] = fmaf(dA, Sv[n], du * Bv);
      Pv[n] *= dA;
    }
  }
  size_t base = ((size_t)(b * NC + c) * NS) * DI + d;
  #pragma unroll
  for (int n = 0; n < NS; ++n) { P[base + (size_t)n * DI] = Pv[n]; S[base + (size_t)n * DI] = Sv[n]; }
}

__global__ __launch_bounds__(256)
void scanB_k(const float* __restrict__ P, const float* __restrict__ S,
             float* __restrict__ hstart)
{
  int g = blockIdx.x * 256 + threadIdx.x;   // < B_*DI = 8192
  int d = g & (DI - 1);
  int b = g >> 11;
  float h[NS];
  #pragma unroll
  for (int n = 0; n < NS; ++n) h[n] = 0.f;
  for (int c = 0; c < NC; ++c) {
    size_t base = ((size_t)(b * NC + c) * NS) * DI + d;
    #pragma unroll
    for (int n = 0; n < NS; ++n) {
      size_t ix = base + (size_t)n * DI;
      hstart[ix] = h[n];
      h[n] = fmaf(P[ix], h[n], S[ix]);
    }
  }
}

__global__ __launch_bounds__(256)
void scanC_k(const u16* __restrict__ uc, const u16* delta,
             const u16* __restrict__ dbl, const u16* __restrict__ xz,
             const u16* __restrict__ Alog, const u16* __restrict__ Dp,
             const float* __restrict__ hstart, u16* ys)  // ys aliases delta
{
  int g = blockIdx.x * 256 + threadIdx.x;   // < B_*NC*DI = 131072
  int d = g & (DI - 1);
  int c = (g >> 11) & (NC - 1);
  int b = g >> 15;
  us8 al0 = *(const us8*)&Alog[d * NS];
  us8 al1 = *(const us8*)&Alog[d * NS + 8];
  float A2[NS], h[NS];
  #pragma unroll
  for (int n = 0; n < 8; ++n) { A2[n] = -__expf(bf2f(al0[n])); A2[n + 8] = -__expf(bf2f(al1[n])); }
  float Dv = bf2f(Dp[d]);
  size_t hbase = ((size_t)(b * NC + c) * NS) * DI + d;
  #pragma unroll
  for (int n = 0; n < NS; ++n) h[n] = hstart[hbase + (size_t)n * DI];
  int t0 = c * CH;
  for (int t = t0; t < t0 + CH; ++t) {
    size_t row = (size_t)b * L_ + t;
    float dv = bf2f(delta[row * DI + d]);
    float uv = bf2f(uc[row * DI + d]);
    float du = dv * uv;
    us8 b0 = *(const us8*)&dbl[row * 96 + 64];
    us8 b1 = *(const us8*)&dbl[row * 96 + 72];
    us8 c0 = *(const us8*)&dbl[row * 96 + 80];
    us8 c1 = *(const us8*)&dbl[row * 96 + 88];
    float y = 0.f;
    #pragma unroll
    for (int n = 0; n < NS; ++n) {
      float Bv = (n < 8) ? bf2f(b0[n & 7]) : bf2f(b1[n & 7]);
      float Cv = (n < 8) ? bf2f(c0[n & 7]) : bf2f(c1[n & 7]);
      float dA = __expf(dv * A2[n]);
      h[n] = fmaf(dA, h[n], du * Bv);
      y = fmaf(h[n], Cv, y);
    }
    float z = bf2f(xz[(row << 12) + DI + d]);
    float out = (y + uv * Dv) * (z / (1.f + __expf(-z)));
    ys[row * DI + d] = f2bf(out);
  }
}

// ---------------------------------------------------------------------------
// Tail elementwise
// ---------------------------------------------------------------------------
__global__ __launch_bounds__(256)
void concat_k(const u16* __restrict__ yf, const u16* __restrict__ yb,
              u16* __restrict__ cat)
{
  int e = blockIdx.x * 256 + threadIdx.x;    // < MT*2*DM
  int c = e & (2 * DM - 1);
  int row = e >> 11;
  int b = row >> 10, t = row & (L_ - 1);
  u16 v;
  if (c < DM) v = yf[((size_t)row << 10) + c];
  else        v = yb[((size_t)(b * L_ + (L_ - 1 - t)) << 10) + (c - DM)];
  cat[e] = v;
}

__global__ __launch_bounds__(256)
void combine_k(const u16* __restrict__ g, const u16* __restrict__ yf,
               const u16* __restrict__ yb, u16* __restrict__ yc)
{
  int e = blockIdx.x * 256 + threadIdx.x;    // < MT*DM
  int c = e & (DM - 1);
  int row = e >> 10;
  int b = row >> 10, t = row & (L_ - 1);
  float gv = bf2f(g[e]);
  float fv = bf2f(yf[e]);
  float bv = bf2f(yb[((size_t)(b * L_ + (L_ - 1 - t)) << 10) + c]);
  yc[e] = f2bf(gv * fv + (1.f - gv) * bv);
}

// ---------------------------------------------------------------------------
// Launch
// ---------------------------------------------------------------------------
extern "C" void kernel_launch(void* const* d_in, const int* in_sizes, int n_in,
                              void* d_out, int out_size, void* d_ws, size_t ws_size,
                              hipStream_t stream)
{
  char* ws = (char*)d_ws;
  const size_t MB = 1ull << 20;
  const size_t KB = 1024;

  // pipeline buffers (bf16)
  u16* xz     = (u16*)(ws + 0);          // 32 MB [MT,4096] (u|z)
  u16* uc     = (u16*)(ws + 32 * MB);    // 16 MB [MT,DI]
  u16* delta  = (u16*)(ws + 48 * MB);    // 16 MB [MT,DI]; ys aliases
  u16* dbl    = (u16*)(ws + 64 * MB);    // 768 KB [MT,96]
  u16* yf     = (u16*)(ws + 65 * MB);    //  8 MB [MT,DM]
  u16* yb     = (u16*)(ws + 73 * MB);    //  8 MB [MT,DM] (flipped time)
  u16* xc     = (u16*)(ws + 81 * MB);    //  8 MB bf16 copy of x
  // transposed weights (shared across dirs, re-transposed per use)
  u16* inproj_t = (u16*)(ws + 89 * MB);  //  8 MB [4096][1024]
  u16* outp_t   = (u16*)(ws + 97 * MB);  //  4 MB [1024][2048]
  u16* xproj_t  = (u16*)(ws + 101 * MB);            // 384 KB [96][2048]
  u16* dtw_t    = (u16*)(ws + 101 * MB + 384 * KB); // 256 KB [2048][64]
  char* SM      = ws + 101 * MB + 640 * KB;         // smalls (384 KB)
  u16* w_alog[2]  = {(u16*)(SM),            (u16*)(SM + 64 * KB)};
  u16* w_convw[2] = {(u16*)(SM + 128 * KB), (u16*)(SM + 144 * KB)};
  u16* w_convb[2] = {(u16*)(SM + 160 * KB), (u16*)(SM + 164 * KB)};
  u16* w_dtb[2]   = {(u16*)(SM + 168 * KB), (u16*)(SM + 172 * KB)};
  u16* w_dp[2]    = {(u16*)(SM + 176 * KB), (u16*)(SM + 180 * KB)};
  u16* w_gb       = (u16*)(SM + 184 * KB);
  u16* w_pb       = (u16*)(SM + 186 * KB);
  int* flag       = (int*)(SM + 188 * KB);
  // scan temporaries (fp32)
  float* Pbuf  = (float*)(ws + 102 * MB);   // 8 MB [B][NC][NS][DI]
  float* Sbuf  = (float*)(ws + 110 * MB);   // 8 MB
  float* hstrt = (float*)(ws + 118 * MB);   // 8 MB   (ends 126 MB)
  // tail overlays
  u16* cat   = xz;                       // 16 MB (xz dead after scans)
  u16* gbuf  = (u16*)(ws + 16 * MB);     //  8 MB
  u16* yc    = uc;                       //  8 MB (uc dead after scans)
  u16* outb  = delta;                    //  8 MB (delta dead after outproj)
  u16* gw_t  = inproj_t;                 //  4 MB (inproj_t dead at tail)
  u16* pw_t  = (u16*)(ws + 93 * MB);     //  2 MB

  dim3 blk(256);
  detect_k<<<1, 1, 0, stream>>>((const unsigned int*)d_in[7], flag);

  auto cvt = [&](const void* src, u16* dst, int n) {
    cvt_k<<<(n + 255) / 256, blk, 0, stream>>>(src, dst, n, flag);
  };
  auto tpose = [&](const void* src, u16* dst, int R, int C) {
    tpose_k<<<dim3(C / 32, R / 32), blk, 0, stream>>>(src, dst, R, C, flag);
  };

  cvt(d_in[0], xc, MT * DM);
  for (int s = 0; s < 2; ++s) {
    int o = 9 * s;
    cvt(d_in[2 + o], w_convw[s], DI * 4);
    cvt(d_in[3 + o], w_convb[s], DI);
    cvt(d_in[6 + o], w_dtb[s], DI);
    cvt(d_in[7 + o], w_alog[s], DI * NS);
    cvt(d_in[8 + o], w_dp[s], DI);
  }
  cvt(d_in[20], w_gb, DM);
  cvt(d_in[22], w_pb, DM);

  for (int s = 0; s < 2; ++s) {
    int o = 9 * s;
    u16* ydir = (s == 0) ? yf : yb;
    // xz = x(@flip if s) @ inproj   [4096 x 4096 x 1024]
    tpose(d_in[1 + o], inproj_t, DM, 2 * DI);
    if (s == 0)
      gemm_mfma<0, 0><<<dim3(32, 32), blk, 0, stream>>>(
          xc, DM, inproj_t, nullptr, xz, 2 * DI, MT, 2 * DI, DM);
    else
      gemm_mfma<0, 1><<<dim3(32, 32), blk, 0, stream>>>(
          xc, DM, inproj_t, nullptr, xz, 2 * DI, MT, 2 * DI, DM);
    // uc = silu(causal_conv(u))
    conv_silu_k<<<MT * DI / 256, blk, 0, stream>>>(xz, w_convw[s], w_convb[s], uc);
    // dbl = uc @ xproj              [4096 x 96 x 2048]
    tpose(d_in[4 + o], xproj_t, DI, 96);
    gemm_mfma<0, 0><<<dim3(1, 32), blk, 0, stream>>>(
        uc, DI, xproj_t, nullptr, dbl, 96, MT, 96, DI);
    // delta = softplus(dbl[:, :64] @ dt_w + dt_b)   [4096 x 2048 x 64]
    tpose(d_in[5 + o], dtw_t, RK, DI);
    gemm_mfma<1, 0><<<dim3(16, 32), blk, 0, stream>>>(
        dbl, 96, dtw_t, w_dtb[s], delta, DI, MT, DI, RK);
    // chunked selective scan (+ skip + z-gate); ys aliases delta
    scanA_k<<<B_ * NC * DI / 256, blk, 0, stream>>>(delta, uc, dbl, w_alog[s], Pbuf, Sbuf);
    scanB_k<<<B_ * DI / 256, blk, 0, stream>>>(Pbuf, Sbuf, hstrt);
    scanC_k<<<B_ * NC * DI / 256, blk, 0, stream>>>(uc, delta, dbl, xz, w_alog[s],
                                                    w_dp[s], hstrt, delta);
    // ydir = ys @ outproj           [4096 x 1024 x 2048]
    tpose(d_in[9 + o], outp_t, DI, DM);
    gemm_mfma<0, 0><<<dim3(8, 32), blk, 0, stream>>>(
        delta, DI, outp_t, nullptr, ydir, DM, MT, DM, DI);
  }

  concat_k<<<MT * 2 * DM / 256, blk, 0, stream>>>(yf, yb, cat);
  // g = sigmoid(cat @ gate_w + gate_b)   [4096 x 1024 x 2048]
  tpose(d_in[19], gw_t, 2 * DM, DM);
  gemm_mfma<2, 0><<<dim3(8, 32), blk, 0, stream>>>(
      cat, 2 * DM, gw_t, w_gb, gbuf, DM, MT, DM, 2 * DM);
  combine_k<<<MT * DM / 256, blk, 0, stream>>>(gbuf, yf, yb, yc);
  // out = yc @ proj_w + proj_b           [4096 x 1024 x 1024]
  tpose(d_in[21], pw_t, DM, DM);
  gemm_mfma<0, 0><<<dim3(8, 32), blk, 0, stream>>>(
      yc, DM, pw_t, w_pb, outb, DM, MT, DM, DM);
  store_out_k<<<MT * DM / 256, blk, 0, stream>>>(outb, d_out, flag);
}

// Round 4
// 1003.571 us; speedup vs baseline: 3.7338x; 1.1573x over previous
//
#include <hip/hip_runtime.h>
#include <hip/hip_bf16.h>

#define B_  4
#define L_  1024
#define DM  1024
#define DI  2048
#define NS  16
#define RK  64
#define MT  (B_ * L_)   // 4096 tokens
#define NC  32          // scan chunks
#define CH  (L_ / NC)   // 32 steps per chunk

typedef unsigned short u16;
typedef __attribute__((ext_vector_type(8))) short  bh8;   // 8 bf16 (4 VGPRs)
typedef __attribute__((ext_vector_type(8))) unsigned short us8;
typedef __attribute__((ext_vector_type(4))) float  f4;

__device__ __forceinline__ float bf2f(u16 u) {
  union { unsigned int i; float f; } c; c.i = ((unsigned int)u) << 16; return c.f;
}
__device__ __forceinline__ u16 f2bf(float f) {
  union { float f; unsigned int i; } c; c.f = f;
  unsigned int x = c.i;
  unsigned int r = (x + 0x7fffu + ((x >> 16) & 1u)) >> 16;  // RNE
  return (u16)r;
}

// ---------------------------------------------------------------------------
// dtype detect: Alog[0]=log(1)=0.  fp32 -> first u32 == 0.  bf16 -> 0x3F310000.
// flag: 1 = bf16 inputs, 0 = fp32 inputs.
// ---------------------------------------------------------------------------
__global__ void detect_k(const unsigned int* __restrict__ alog, int* __restrict__ flag) {
  *flag = (alog[0] != 0u) ? 1 : 0;
}

// one dispatch for all small weight tensors (convw/convb/dtb/dp x2, gb, pb)
__global__ __launch_bounds__(256)
void cvt10_k(const int* __restrict__ flagp,
             const void* s0, u16* d0, int n0, const void* s1, u16* d1, int n1,
             const void* s2, u16* d2, int n2, const void* s3, u16* d3, int n3,
             const void* s4, u16* d4, int n4, const void* s5, u16* d5, int n5,
             const void* s6, u16* d6, int n6, const void* s7, u16* d7, int n7,
             const void* s8, u16* d8, int n8, const void* s9, u16* d9, int n9)
{
  const void* s; u16* d; int n;
  switch (blockIdx.y) {
    case 0: s = s0; d = d0; n = n0; break;  case 1: s = s1; d = d1; n = n1; break;
    case 2: s = s2; d = d2; n = n2; break;  case 3: s = s3; d = d3; n = n3; break;
    case 4: s = s4; d = d4; n = n4; break;  case 5: s = s5; d = d5; n = n5; break;
    case 6: s = s6; d = d6; n = n6; break;  case 7: s = s7; d = d7; n = n7; break;
    case 8: s = s8; d = d8; n = n8; break;  default: s = s9; d = d9; n = n9; break;
  }
  int i = blockIdx.x * 256 + threadIdx.x;
  if (i >= n) return;
  d[i] = *flagp ? ((const u16*)s)[i] : f2bf(((const float*)s)[i]);
}

// A2[dir][d][n] = -exp(Alog[d][n]) fp32, both directions in one dispatch
__global__ __launch_bounds__(256)
void a2_k(const int* __restrict__ flagp, const void* __restrict__ sf,
          const void* __restrict__ sb, float* __restrict__ A2f)
{
  int i = blockIdx.x * 256 + threadIdx.x;   // < 2*DI*NS
  const void* src = (i < DI * NS) ? sf : sb;
  int j = i & (DI * NS - 1);
  float v = *flagp ? bf2f(((const u16*)src)[j]) : ((const float*)src)[j];
  A2f[i] = -__expf(v);
}

// ---------------------------------------------------------------------------
// Tiled transpose with dtype convert: src[R][C] (flag dtype) -> dst[C][R] bf16.
// ---------------------------------------------------------------------------
__global__ __launch_bounds__(256)
void tpose_k(const void* __restrict__ src, u16* __restrict__ dst,
             int R, int C, const int* __restrict__ flag) {
  __shared__ u16 tile[32][33];
  int c0 = blockIdx.x * 32, r0 = blockIdx.y * 32;
  int tx = threadIdx.x & 31, ty = threadIdx.x >> 5;   // ty 0..7
  int isbf = *flag;
  #pragma unroll
  for (int i = 0; i < 4; ++i) {
    int r = r0 + ty + i * 8, c = c0 + tx;
    u16 v = 0;
    if (r < R && c < C)
      v = isbf ? ((const u16*)src)[(size_t)r * C + c]
               : f2bf(((const float*)src)[(size_t)r * C + c]);
    tile[ty + i * 8][tx] = v;
  }
  __syncthreads();
  #pragma unroll
  for (int i = 0; i < 4; ++i) {
    int c = c0 + ty + i * 8, r = r0 + tx;
    if (c < C && r < R)
      dst[(size_t)c * R + r] = tile[tx][ty + i * 8];
  }
}

// ---------------------------------------------------------------------------
// MFMA GEMM: C[M,N] = act(A[M,K] @ W[K,N] + bias), Wt[N][K] pre-transposed.
// 128x128 tile, BK=32, 4 waves, 4x4 mfma_f32_16x16x32_bf16, fp32 accum.
// FLIP: A rows time-reversed (row^1023).  SRCF: A is raw input, dtype by flag.
// CATM: A[k<1024]=yf[m][k], A[k>=1024]=yb[m^1023][k-1024]  (fused concat).
// ACT: 0 none, 1 softplus, 3 sigmoid-gate-combine (writes blended yf/yb).
// OUTF: write C in flag dtype (fused final store).
// ---------------------------------------------------------------------------
template<int ACT, int FLIP, int SRCF, int CATM, int OUTF>
__global__ __launch_bounds__(256, 2)
void gemm_mfma(const void* __restrict__ A, int lda,
               const u16* __restrict__ Wt,
               const u16* __restrict__ bias,
               void* __restrict__ Cp, int ldc,
               int M, int N, int K,
               const u16* __restrict__ yfp, const u16* __restrict__ ybp,
               const int* __restrict__ flagp)
{
  __shared__ __align__(16) u16 As[128][40];   // +8 pad
  __shared__ __align__(16) u16 Bs[128][40];

  const int tid  = threadIdx.x;
  const int lane = tid & 63;
  const int w    = tid >> 6;
  const int wm   = (w >> 1) * 64, wn = (w & 1) * 64;
  const int bm0  = blockIdx.y * 128, bn0 = blockIdx.x * 128;
  const int l15  = lane & 15, quad = lane >> 4;
  const int ar   = tid >> 2;            // 0..63
  const int ak   = (tid & 3) * 8;       // 0,8,16,24
  const int isf32 = SRCF ? (*flagp == 0) : 0;

  f4 acc[4][4] = {};

  for (int k0 = 0; k0 < K; k0 += 32) {
    #pragma unroll
    for (int h = 0; h < 2; ++h) {
      int m = bm0 + ar + h * 64;
      int msrc = FLIP ? (m ^ (L_ - 1)) : m;
      bh8 av;
      if (CATM) {
        int k = k0 + ak;
        const u16* src = (k < DM) ? (yfp + (size_t)m * DM + k)
                                  : (ybp + (size_t)(m ^ (L_ - 1)) * DM + (k - DM));
        av = *(const bh8*)src;
      } else if (SRCF && isf32) {
        const float* ap = (const float*)A + (size_t)msrc * lda + k0 + ak;
        float4 f0 = ((const float4*)ap)[0], f1 = ((const float4*)ap)[1];
        av[0] = (short)f2bf(f0.x); av[1] = (short)f2bf(f0.y);
        av[2] = (short)f2bf(f0.z); av[3] = (short)f2bf(f0.w);
        av[4] = (short)f2bf(f1.x); av[5] = (short)f2bf(f1.y);
        av[6] = (short)f2bf(f1.z); av[7] = (short)f2bf(f1.w);
      } else {
        av = *(const bh8*)((const u16*)A + (size_t)msrc * lda + k0 + ak);
      }
      *(bh8*)&As[ar + h * 64][ak] = av;
      int n = bn0 + ar + h * 64;
      bh8 bv = {0, 0, 0, 0, 0, 0, 0, 0};
      if (n < N) bv = *(const bh8*)(Wt + (size_t)n * K + k0 + ak);
      *(bh8*)&Bs[ar + h * 64][ak] = bv;
    }
    __syncthreads();
    bh8 af[4], bf[4];
    #pragma unroll
    for (int i = 0; i < 4; ++i) {
      af[i] = *(const bh8*)&As[wm + i * 16 + l15][quad * 8];
      bf[i] = *(const bh8*)&Bs[wn + i * 16 + l15][quad * 8];
    }
    #pragma unroll
    for (int i = 0; i < 4; ++i)
      #pragma unroll
      for (int j = 0; j < 4; ++j)
        acc[i][j] = __builtin_amdgcn_mfma_f32_16x16x32_bf16(af[i], bf[j], acc[i][j], 0, 0, 0);
    __syncthreads();
  }

  const int obf = OUTF ? *flagp : 1;
  #pragma unroll
  for (int j = 0; j < 4; ++j) {
    int col = bn0 + wn + j * 16 + l15;
    if (col >= N) continue;
    float bv = bias ? bf2f(bias[col]) : 0.f;
    #pragma unroll
    for (int i = 0; i < 4; ++i) {
      #pragma unroll
      for (int r = 0; r < 4; ++r) {
        int row = bm0 + wm + i * 16 + quad * 4 + r;
        float v = acc[i][j][r] + bv;
        if (ACT == 1) v = (v > 20.f) ? v : log1pf(__expf(v));
        if (ACT == 3) {
          float g = 1.f / (1.f + __expf(-v));
          float fv = bf2f(yfp[(size_t)row * DM + col]);
          float bb = bf2f(ybp[(size_t)(row ^ (L_ - 1)) * DM + col]);
          v = g * fv + (1.f - g) * bb;
        }
        if (OUTF && !obf) ((float*)Cp)[(size_t)row * ldc + col] = v;
        else              ((u16*)Cp)[(size_t)row * ldc + col] = f2bf(v);
      }
    }
  }
}

// ---------------------------------------------------------------------------
// Depthwise causal conv1d (width 4) + SiLU.  u lives in xz cols [0, DI).
// ---------------------------------------------------------------------------
__global__ __launch_bounds__(256)
void conv_silu_k(const u16* __restrict__ xz,   // [MT, 2*DI]
                 const u16* __restrict__ cw,   // [DI, 4]
                 const u16* __restrict__ cb,   // [DI]
                 u16* __restrict__ uc)         // [MT, DI]
{
  int e = blockIdx.x * 256 + threadIdx.x;      // < MT*DI
  int d = e & (DI - 1);
  int t = (e >> 11) & (L_ - 1);
  int b = e >> 21;
  float acc = bf2f(cb[d]);
  #pragma unroll
  for (int k = 0; k < 4; ++k) {
    int ts = t + k - 3;
    if (ts >= 0)
      acc += bf2f(xz[((size_t)(b * L_ + ts) << 12) + d]) * bf2f(cw[(d << 2) + k]);
  }
  uc[(size_t)e] = f2bf(acc / (1.f + __expf(-acc)));
}

// ---------------------------------------------------------------------------
// Chunked selective scan, NC=32 chunks of CH=32.  Thread = (b, c, d).
// Pass A: per-chunk affine map (P,S) fp16.  Pass B: compose; h_start stored
// in-place into P.  Pass C: re-run chunk from h_start, emit gated y.
// ---------------------------------------------------------------------------
__global__ __launch_bounds__(256, 4)
void scanA_k(const u16* __restrict__ delta, const u16* __restrict__ uc,
             const u16* __restrict__ dbl, const float* __restrict__ A2f,
             _Float16* __restrict__ P, _Float16* __restrict__ S)
{
  int g = blockIdx.x * 256 + threadIdx.x;   // < B_*NC*DI
  int d = g & (DI - 1);
  int c = (g >> 11) & (NC - 1);
  int b = g >> 16;
  float A2[NS], Pv[NS], Sv[NS];
  #pragma unroll
  for (int q = 0; q < 4; ++q)
    *(float4*)&A2[q * 4] = ((const float4*)(A2f + d * NS))[q];
  #pragma unroll
  for (int n = 0; n < NS; ++n) { Pv[n] = 1.f; Sv[n] = 0.f; }
  int t0 = c * CH;
  for (int t = t0; t < t0 + CH; ++t) {
    size_t row = (size_t)b * L_ + t;
    float dv = bf2f(delta[row * DI + d]);
    float uv = bf2f(uc[row * DI + d]);
    float du = dv * uv;
    us8 b0 = *(const us8*)&dbl[row * 96 + 64];
    us8 b1 = *(const us8*)&dbl[row * 96 + 72];
    #pragma unroll
    for (int n = 0; n < NS; ++n) {
      float Bv = (n < 8) ? bf2f(b0[n & 7]) : bf2f(b1[n & 7]);
      float dA = __expf(dv * A2[n]);
      Sv[n] = fmaf(dA, Sv[n], du * Bv);
      Pv[n] *= dA;
    }
  }
  size_t base = ((size_t)(b * NC + c) * NS) * DI + d;
  #pragma unroll
  for (int n = 0; n < NS; ++n) {
    P[base + (size_t)n * DI] = (_Float16)Pv[n];
    S[base + (size_t)n * DI] = (_Float16)Sv[n];
  }
}

__global__ __launch_bounds__(256)
void scanB_k(_Float16* __restrict__ P, const _Float16* __restrict__ S)
{
  int g = blockIdx.x * 256 + threadIdx.x;   // < B_*NS*DI = 131072
  int d = g & (DI - 1);
  int n = (g >> 11) & (NS - 1);
  int b = g >> 15;
  float h = 0.f;
  #pragma unroll 4
  for (int c = 0; c < NC; ++c) {
    size_t ix = ((size_t)(b * NC + c) * NS + n) * DI + d;
    float p = (float)P[ix], s = (float)S[ix];
    P[ix] = (_Float16)h;                    // h_start for chunk c (in-place)
    h = fmaf(p, h, s);
  }
}

__global__ __launch_bounds__(256, 4)
void scanC_k(const u16* __restrict__ uc, const u16* delta,
             const u16* __restrict__ dbl, const u16* __restrict__ xz,
             const float* __restrict__ A2f, const u16* __restrict__ Dp,
             const _Float16* __restrict__ hstart, u16* ys)  // ys aliases delta
{
  int g = blockIdx.x * 256 + threadIdx.x;   // < B_*NC*DI
  int d = g & (DI - 1);
  int c = (g >> 11) & (NC - 1);
  int b = g >> 16;
  float A2[NS], h[NS];
  #pragma unroll
  for (int q = 0; q < 4; ++q)
    *(float4*)&A2[q * 4] = ((const float4*)(A2f + d * NS))[q];
  float Dv = bf2f(Dp[d]);
  size_t hbase = ((size_t)(b * NC + c) * NS) * DI + d;
  #pragma unroll
  for (int n = 0; n < NS; ++n) h[n] = (float)hstart[hbase + (size_t)n * DI];
  int t0 = c * CH;
  for (int t = t0; t < t0 + CH; ++t) {
    size_t row = (size_t)b * L_ + t;
    float dv = bf2f(delta[row * DI + d]);
    float uv = bf2f(uc[row * DI + d]);
    float du = dv * uv;
    us8 b0 = *(const us8*)&dbl[row * 96 + 64];
    us8 b1 = *(const us8*)&dbl[row * 96 + 72];
    us8 c0 = *(const us8*)&dbl[row * 96 + 80];
    us8 c1 = *(const us8*)&dbl[row * 96 + 88];
    float y = 0.f;
    #pragma unroll
    for (int n = 0; n < NS; ++n) {
      float Bv = (n < 8) ? bf2f(b0[n & 7]) : bf2f(b1[n & 7]);
      float Cv = (n < 8) ? bf2f(c0[n & 7]) : bf2f(c1[n & 7]);
      float dA = __expf(dv * A2[n]);
      h[n] = fmaf(dA, h[n], du * Bv);
      y = fmaf(h[n], Cv, y);
    }
    float z = bf2f(xz[(row << 12) + DI + d]);
    float out = (y + uv * Dv) * (z / (1.f + __expf(-z)));
    ys[row * DI + d] = f2bf(out);
  }
}

// ---------------------------------------------------------------------------
// Launch
// ---------------------------------------------------------------------------
extern "C" void kernel_launch(void* const* d_in, const int* in_sizes, int n_in,
                              void* d_out, int out_size, void* d_ws, size_t ws_size,
                              hipStream_t stream)
{
  char* ws = (char*)d_ws;
  const size_t MB = 1ull << 20;
  const size_t KB = 1024;

  u16* xz     = (u16*)(ws + 0);          // 32 MB [MT,4096] (u|z)
  u16* uc     = (u16*)(ws + 32 * MB);    // 16 MB [MT,DI]
  u16* delta  = (u16*)(ws + 48 * MB);    // 16 MB [MT,DI]; ys alias
  u16* dbl    = (u16*)(ws + 64 * MB);    // 768 KB [MT,96]
  u16* yf     = (u16*)(ws + 65 * MB);    //  8 MB [MT,DM]
  u16* yb     = (u16*)(ws + 73 * MB);    //  8 MB [MT,DM] (flipped time)
  u16* inproj_t = (u16*)(ws + 81 * MB);  //  8 MB [4096][1024]
  u16* outp_t   = (u16*)(ws + 89 * MB);  //  4 MB [1024][2048]
  u16* xproj_t  = (u16*)(ws + 93 * MB);             // 384 KB [96][2048]
  u16* dtw_t    = (u16*)(ws + 93 * MB + 512 * KB);  // 256 KB [2048][64]
  char* SM      = ws + 94 * MB;
  u16* w_convw[2] = {(u16*)(SM),           (u16*)(SM + 16 * KB)};
  u16* w_convb[2] = {(u16*)(SM + 32 * KB), (u16*)(SM + 36 * KB)};
  u16* w_dtb[2]   = {(u16*)(SM + 40 * KB), (u16*)(SM + 44 * KB)};
  u16* w_dp[2]    = {(u16*)(SM + 48 * KB), (u16*)(SM + 52 * KB)};
  u16* w_gb       = (u16*)(SM + 56 * KB);
  u16* w_pb       = (u16*)(SM + 58 * KB);
  int* flag       = (int*)(SM + 60 * KB);
  float* A2f      = (float*)(SM + 64 * KB);   // 256 KB [2][DI][NS]
  _Float16* Pbuf  = (_Float16*)(ws + 95 * MB);   // 8 MB [B][NC][NS][DI]
  _Float16* Sbuf  = (_Float16*)(ws + 103 * MB);  // 8 MB  (ends 111 MB)
  // tail overlays
  u16* yc   = uc;                        // uc dead after scanC s=1
  u16* gw_t = inproj_t;                  // dead at tail; 4 MB needed
  u16* pw_t = outp_t;                    // dead after outproj s=1; 2 MB

  dim3 blk(256);
  detect_k<<<1, 1, 0, stream>>>((const unsigned int*)d_in[7], flag);

  cvt10_k<<<dim3(32, 10), blk, 0, stream>>>(flag,
      d_in[2],  w_convw[0], DI * 4, d_in[3],  w_convb[0], DI,
      d_in[6],  w_dtb[0],   DI,     d_in[8],  w_dp[0],    DI,
      d_in[11], w_convw[1], DI * 4, d_in[12], w_convb[1], DI,
      d_in[15], w_dtb[1],   DI,     d_in[17], w_dp[1],    DI,
      d_in[20], w_gb,       DM,     d_in[22], w_pb,       DM);
  a2_k<<<2 * DI * NS / 256, blk, 0, stream>>>(flag, d_in[7], d_in[16], A2f);

  auto tpose = [&](const void* src, u16* dst, int R, int C) {
    tpose_k<<<dim3(C / 32, R / 32), blk, 0, stream>>>(src, dst, R, C, flag);
  };

  for (int s = 0; s < 2; ++s) {
    int o = 9 * s;
    u16* ydir = (s == 0) ? yf : yb;
    // xz = x(flip if s) @ inproj   [4096 x 4096 x 1024], A = raw x (flag dtype)
    tpose(d_in[1 + o], inproj_t, DM, 2 * DI);
    if (s == 0)
      gemm_mfma<0, 0, 1, 0, 0><<<dim3(32, 32), blk, 0, stream>>>(
          d_in[0], DM, inproj_t, nullptr, xz, 2 * DI, MT, 2 * DI, DM,
          nullptr, nullptr, flag);
    else
      gemm_mfma<0, 1, 1, 0, 0><<<dim3(32, 32), blk, 0, stream>>>(
          d_in[0], DM, inproj_t, nullptr, xz, 2 * DI, MT, 2 * DI, DM,
          nullptr, nullptr, flag);
    conv_silu_k<<<MT * DI / 256, blk, 0, stream>>>(xz, w_convw[s], w_convb[s], uc);
    // dbl = uc @ xproj   [4096 x 96 x 2048]
    tpose(d_in[4 + o], xproj_t, DI, 96);
    gemm_mfma<0, 0, 0, 0, 0><<<dim3(1, 32), blk, 0, stream>>>(
        uc, DI, xproj_t, nullptr, dbl, 96, MT, 96, DI, nullptr, nullptr, flag);
    // delta = softplus(dbl[:,:64] @ dt_w + dt_b)   [4096 x 2048 x 64]
    tpose(d_in[5 + o], dtw_t, RK, DI);
    gemm_mfma<1, 0, 0, 0, 0><<<dim3(16, 32), blk, 0, stream>>>(
        dbl, 96, dtw_t, w_dtb[s], delta, DI, MT, DI, RK, nullptr, nullptr, flag);
    // chunked scan (+ skip + z-gate); ys aliases delta; hstart in-place in P
    scanA_k<<<B_ * NC * DI / 256, blk, 0, stream>>>(delta, uc, dbl, A2f + s * DI * NS,
                                                    Pbuf, Sbuf);
    scanB_k<<<B_ * NS * DI / 256, blk, 0, stream>>>(Pbuf, Sbuf);
    scanC_k<<<B_ * NC * DI / 256, blk, 0, stream>>>(uc, delta, dbl, xz,
                                                    A2f + s * DI * NS, w_dp[s],
                                                    Pbuf, delta);
    // ydir = ys @ outproj   [4096 x 1024 x 2048]
    tpose(d_in[9 + o], outp_t, DI, DM);
    gemm_mfma<0, 0, 0, 0, 0><<<dim3(8, 32), blk, 0, stream>>>(
        delta, DI, outp_t, nullptr, ydir, DM, MT, DM, DI, nullptr, nullptr, flag);
  }

  // yc = sigmoid([yf|yb_unflip] @ gate_w + gate_b) blend of yf/yb (all fused)
  tpose(d_in[19], gw_t, 2 * DM, DM);
  gemm_mfma<3, 0, 0, 1, 0><<<dim3(8, 32), blk, 0, stream>>>(
      yf, DM, gw_t, w_gb, yc, DM, MT, DM, 2 * DM, yf, yb, flag);
  // out = yc @ proj_w + proj_b  -> d_out in detected dtype
  tpose(d_in[21], pw_t, DM, DM);
  gemm_mfma<0, 0, 0, 0, 1><<<dim3(8, 32), blk, 0, stream>>>(
      yc, DM, pw_t, w_pb, d_out, DM, MT, DM, DM, nullptr, nullptr, flag);
}